// Round 15
// baseline (421.818 us; speedup 1.0000x reference)
//
#include <hip/hip_runtime.h>
#include <hip/hip_bf16.h>
#include <math.h>

// Problem constants
#define DM 96
#define DI 192
#define DSTATE 64
#define NH 8
#define HD 24
#define CD 320
#define ZD 520
#define LSEQ 512
#define NSEQ 24            // B(2) * 12 directions
#define NROW (NSEQ*LSEQ)   // 12288
#define LC 64              // scan chunk length
#define NCH (LSEQ/LC)      // 8 chunks

typedef __attribute__((ext_vector_type(8))) short short8;
typedef __attribute__((ext_vector_type(4))) float f32x4;

__device__ __forceinline__ float wave_sum64(float v){
  #pragma unroll
  for (int o = 32; o > 0; o >>= 1) v += __shfl_down(v, o);
  return v;
}

__device__ __forceinline__ float silu_f(float x){
  return x / (1.f + expf(-x));
}

__device__ __forceinline__ short bf16s(float v){
  __hip_bfloat16 b = __float2bfloat16(v);
  return *reinterpret_cast<short*>(&b);
}

// ---------------------------------------------------------------------------
// 1+0) merged: downsample (blocks 0..1023) | weight bf16 convert (rest)
#define WIP 49920            // 520*96
#define WOP 18432            // 96*192
#define WF1 18432            // 192*96
#define WF2 18432            // 96*192
#define WPL (WIP+WOP+WF1+WF2)  // 105216
#define WCB ((2*WPL + 127)/128)  // 1644 wcvt blocks
__global__ void k_dswcvt(const float* __restrict__ x,
                         const float* __restrict__ lnw,
                         const float* __restrict__ lnb,
                         const float* __restrict__ redw,
                         float* __restrict__ res,
                         const float* __restrict__ ipw, const float* __restrict__ opw,
                         const float* __restrict__ f1w, const float* __restrict__ f2w,
                         __hip_bfloat16* __restrict__ Wb){
  int tid = threadIdx.x;
  if (blockIdx.x >= 1024){
    int idx = (blockIdx.x - 1024)*128 + tid;
    if (idx < 2*WPL){
      int l = idx / WPL, r = idx % WPL;
      float v;
      if (r < WIP)                 v = ipw[(size_t)l*WIP + r];
      else if (r < WIP+WOP)        v = opw[(size_t)l*WOP + (r-WIP)];
      else if (r < WIP+WOP+WF1)    v = f1w[(size_t)l*WF1 + (r-WIP-WOP)];
      else                         v = f2w[(size_t)l*WF2 + (r-WIP-WOP-WF1)];
      Wb[idx] = __float2bfloat16(v);
    }
    return;
  }
  int vox = blockIdx.x;
  int b = vox >> 9; int r = vox & 511;
  int i = r >> 6, j = (r >> 3) & 7, k = r & 7;
  __shared__ float t[384];
  __shared__ float sm[4];
  for (int f = tid; f < 384; f += 128){
    int c = f >> 3; int di = (f >> 2) & 1, dj = (f >> 1) & 1, dk = f & 1;
    int X = 2*i + di, Y = 2*j + dj, Z = 2*k + dk;
    t[f] = x[(((b*48 + c)*16 + X)*16 + Y)*16 + Z];
  }
  __syncthreads();
  float s = 0.f, s2 = 0.f;
  for (int f = tid; f < 384; f += 128){ float v = t[f]; s += v; s2 += v*v; }
  s = wave_sum64(s); s2 = wave_sum64(s2);
  int lane = tid & 63, wv = tid >> 6;
  if (lane == 0){ sm[wv] = s; sm[2+wv] = s2; }
  __syncthreads();
  float mean = (sm[0] + sm[1]) * (1.f/384.f);
  float var  = (sm[2] + sm[3]) * (1.f/384.f) - mean*mean;
  float rstd = rsqrtf(var + 1e-5f);
  __syncthreads();
  for (int f = tid; f < 384; f += 128) t[f] = (t[f]-mean)*rstd*lnw[f] + lnb[f];
  __syncthreads();
  if (tid < 96){
    const float* wrow = redw + tid*384;
    float acc = 0.f;
    #pragma unroll 4
    for (int f = 0; f < 384; f++) acc = fmaf(t[f], wrow[f], acc);
    res[((b*96 + tid)*512) + r] = acc;
  }
}

// ---------------------------------------------------------------------------
// 2+3) build H row + layer-0 LN1 -> Ub (bf16).  grid = NROW, 128 thr.
__global__ void k_build_ln(const float* __restrict__ res, float* __restrict__ H,
                           __hip_bfloat16* __restrict__ Ub,
                           const float* __restrict__ w, const float* __restrict__ bias){
  int row = blockIdx.x;           // s*LSEQ + t
  int s = row >> 9; int t = row & 511;
  int tid = threadIdx.x;
  float v = 0.f;
  if (tid < DM){
    int b = s / 12, d = s % 12;
    int tt = (d & 2) ? (511 - t) : t;
    int a = tt >> 6, bb = (tt >> 3) & 7, cc = tt & 7;
    int i, j, k;
    int g = d >> 2; bool sw = d & 1;
    if (g == 0){ if (!sw){ i=a; j=bb; k=cc; } else { i=a; k=bb; j=cc; } }
    else if (g == 1){ if (!sw){ j=a; k=bb; i=cc; } else { j=a; i=bb; k=cc; } }
    else { if (!sw){ k=a; i=bb; j=cc; } else { k=a; j=bb; i=cc; } }
    v = res[((b*96 + tid)*512) + (i*64 + j*8 + k)];
  }
  float sv = wave_sum64(v), s2 = wave_sum64(v*v);
  __shared__ float sm[4];
  int lane = tid & 63, wv = tid >> 6;
  if (lane == 0){ sm[wv] = sv; sm[2+wv] = s2; }
  __syncthreads();
  float mean = (sm[0] + sm[1]) * (1.f/96.f);
  float var  = (sm[2] + sm[3]) * (1.f/96.f) - mean*mean;
  float rstd = rsqrtf(var + 1e-5f);
  if (tid < DM){
    H[(size_t)row*DM + tid] = v;
    Ub[(size_t)row*DM + tid] = __float2bfloat16((v-mean)*rstd*w[tid] + bias[tid]);
  }
}

// ---------------------------------------------------------------------------
// 4a) plain MFMA GEMM (bf16 A), full-K LDS stage, TPG n-tiles per y-block.
#define LDA 200   // LDS row stride in ushorts
template<int ACT, int OBF>
__global__ __launch_bounds__(256)
void k_gemm_m2(const ushort* __restrict__ A, const ushort* __restrict__ W,
               const float* __restrict__ bias, float* __restrict__ C,
               __hip_bfloat16* __restrict__ Cb, int N, int K, int TPG){
  __shared__ ushort As[64*LDA];
  __shared__ ushort Ws[64*LDA];
  int m0 = blockIdx.x * 64;
  int tid = threadIdx.x;
  int lane = tid & 63, w = tid >> 6;
  int CPR = K >> 3;
  for (int u = tid; u < 64*CPR; u += 256){
    int row = u / CPR, cc = u % CPR;
    *(short8*)&As[row*LDA + cc*8] =
        *(const short8*)(A + (size_t)(m0+row)*K + cc*8);
  }
  __syncthreads();

  int ntiles = (N + 63) >> 6;
  int nt0 = blockIdx.y * TPG;
  int nt1 = nt0 + TPG; if (nt1 > ntiles) nt1 = ntiles;
  int kb = (lane >> 4) * 8;

  for (int nt = nt0; nt < nt1; ++nt){
    int n0 = nt * 64;
    for (int u = tid; u < 64*CPR; u += 256){
      int row = u / CPR, cc = u % CPR;
      int n = n0 + row;
      short8 wv = {0,0,0,0,0,0,0,0};
      if (n < N) wv = *(const short8*)(W + (size_t)n*K + cc*8);
      *(short8*)&Ws[row*LDA + cc*8] = wv;
    }
    __syncthreads();

    f32x4 acc[4];
    #pragma unroll
    for (int i = 0; i < 4; i++) acc[i] = (f32x4){0.f,0.f,0.f,0.f};
    for (int ks = 0; ks < (K >> 5); ++ks){
      short8 b = *(short8*)&Ws[(w*16 + (lane&15))*LDA + ks*32 + kb];
      #pragma unroll
      for (int i = 0; i < 4; i++){
        short8 a = *(short8*)&As[(i*16 + (lane&15))*LDA + ks*32 + kb];
        acc[i] = __builtin_amdgcn_mfma_f32_16x16x32_bf16(a, b, acc[i], 0, 0, 0);
      }
    }

    int nn = n0 + w*16 + (lane & 15);
    if (nn < N){
      float bv = bias ? bias[nn] : 0.f;
      #pragma unroll
      for (int i = 0; i < 4; i++){
        int lrow0 = i*16 + ((lane >> 4) << 2);
        #pragma unroll
        for (int r = 0; r < 4; r++){
          float v = acc[i][r] + bv;
          if (ACT == 1) v = 0.5f*v*(1.f + erff(v*0.70710678118654752f));
          size_t off = (size_t)(m0 + lrow0 + r)*N + nn;
          if (OBF) Cb[off] = __float2bfloat16(v);
          else     C[off] = v;
        }
      }
    }
    __syncthreads();
  }
}

// ---------------------------------------------------------------------------
// 4b) fused-output GEMM: N==96, K==192, grid (192,1).
//     S = A.W^T (+bias) + Rold ;  Rnew = S ;  U = LN(S)*lnw + lnb.
template<int UF32>
__global__ __launch_bounds__(256)
void k_gemm_fuse(const ushort* __restrict__ A, const ushort* __restrict__ W,
                 const float* __restrict__ bias,
                 const float* __restrict__ Rold, float* __restrict__ Rnew,
                 const float* __restrict__ lnw, const float* __restrict__ lnb,
                 void* __restrict__ Uo){
  __shared__ ushort As[64*LDA];
  __shared__ ushort Ws[64*LDA];
  __shared__ float Ct[64][100];
  const int K = 192, N = 96, CPR = 24;
  int m0 = blockIdx.x * 64;
  int tid = threadIdx.x;
  int lane = tid & 63, w = tid >> 6;
  for (int u = tid; u < 64*CPR; u += 256){
    int row = u / CPR, cc = u % CPR;
    *(short8*)&As[row*LDA + cc*8] =
        *(const short8*)(A + (size_t)(m0+row)*K + cc*8);
  }
  __syncthreads();

  int kb = (lane >> 4) * 8;
  for (int nt = 0; nt < 2; ++nt){
    int n0 = nt * 64;
    for (int u = tid; u < 64*CPR; u += 256){
      int row = u / CPR, cc = u % CPR;
      int n = n0 + row;
      short8 wv = {0,0,0,0,0,0,0,0};
      if (n < N) wv = *(const short8*)(W + (size_t)n*K + cc*8);
      *(short8*)&Ws[row*LDA + cc*8] = wv;
    }
    __syncthreads();

    f32x4 acc[4];
    #pragma unroll
    for (int i = 0; i < 4; i++) acc[i] = (f32x4){0.f,0.f,0.f,0.f};
    for (int ks = 0; ks < 6; ++ks){
      short8 b = *(short8*)&Ws[(w*16 + (lane&15))*LDA + ks*32 + kb];
      #pragma unroll
      for (int i = 0; i < 4; i++){
        short8 a = *(short8*)&As[(i*16 + (lane&15))*LDA + ks*32 + kb];
        acc[i] = __builtin_amdgcn_mfma_f32_16x16x32_bf16(a, b, acc[i], 0, 0, 0);
      }
    }

    int nn = n0 + w*16 + (lane & 15);
    if (nn < N){
      float bv = bias ? bias[nn] : 0.f;
      #pragma unroll
      for (int i = 0; i < 4; i++){
        int lrow0 = i*16 + ((lane >> 4) << 2);
        #pragma unroll
        for (int r = 0; r < 4; r++)
          Ct[lrow0 + r][nn] = acc[i][r] + bv;
      }
    }
    __syncthreads();
  }

  // epilogue: residual add + LN over the full 96-wide row
  int row = tid >> 2, part = tid & 3;
  size_t g = (size_t)(m0 + row)*96 + part*24;
  float sv[24];
  float s = 0.f, s2 = 0.f;
  #pragma unroll
  for (int i = 0; i < 24; i += 4){
    float4 rv = *(const float4*)(Rold + g + i);
    float v0 = Ct[row][part*24 + i + 0] + rv.x;
    float v1 = Ct[row][part*24 + i + 1] + rv.y;
    float v2 = Ct[row][part*24 + i + 2] + rv.z;
    float v3 = Ct[row][part*24 + i + 3] + rv.w;
    sv[i] = v0; sv[i+1] = v1; sv[i+2] = v2; sv[i+3] = v3;
    s += v0+v1+v2+v3;
    s2 += v0*v0+v1*v1+v2*v2+v3*v3;
  }
  s += __shfl_xor(s, 1); s += __shfl_xor(s, 2);
  s2 += __shfl_xor(s2, 1); s2 += __shfl_xor(s2, 2);
  float mu = s * (1.f/96.f);
  float rstd = rsqrtf(s2 * (1.f/96.f) - mu*mu + 1e-5f);
  #pragma unroll
  for (int i = 0; i < 24; i += 4)
    *(float4*)(Rnew + g + i) = make_float4(sv[i], sv[i+1], sv[i+2], sv[i+3]);
  if (UF32){
    float* Uf = (float*)Uo;
    #pragma unroll
    for (int i = 0; i < 24; i += 4){
      int c = part*24 + i;
      *(float4*)(Uf + g + i) = make_float4(
        (sv[i]  -mu)*rstd*lnw[c]   + lnb[c],
        (sv[i+1]-mu)*rstd*lnw[c+1] + lnb[c+1],
        (sv[i+2]-mu)*rstd*lnw[c+2] + lnb[c+2],
        (sv[i+3]-mu)*rstd*lnw[c+3] + lnb[c+3]);
    }
  } else {
    ushort* Ub = (ushort*)Uo;
    #pragma unroll
    for (int v8 = 0; v8 < 3; ++v8){
      short8 o;
      #pragma unroll
      for (int j = 0; j < 8; j++){
        int c = part*24 + v8*8 + j;
        o[j] = bf16s((sv[v8*8+j]-mu)*rstd*lnw[c] + lnb[c]);
      }
      *(short8*)(Ub + g + v8*8) = o;
    }
  }
}

// ---------------------------------------------------------------------------
// 4c) out_proj with SINGLE-PASS gate prologue + residual/LN epilogue.
//     g = (Y + YP1+YP2+YP3 + Dv*xh) * silu(z); As = bf16(g*nw); rs applied
//     at the Ct write (RMS commutes with GEMM). Then Rnew = Rold + S; Ub = LN2.
__global__ __launch_bounds__(256)
void k_gemm_gate(const float* __restrict__ Y, const float* __restrict__ YP3,
                 const float* __restrict__ XBC, const float* __restrict__ ZX,
                 const float* __restrict__ Dv, const float* __restrict__ nw,
                 const ushort* __restrict__ W,
                 const float* __restrict__ Rold, float* __restrict__ Rnew,
                 const float* __restrict__ lnw, const float* __restrict__ lnb,
                 __hip_bfloat16* __restrict__ Ubo){
  __shared__ ushort As[64*LDA];
  __shared__ ushort Ws[64*LDA];
  __shared__ float Ct[64][100];
  __shared__ float sRs[64];
  const int K = 192, N = 96, CPR = 24;
  const size_t PS = (size_t)NROW*DI;
  int m0 = blockIdx.x * 64;
  int tid = threadIdx.x;
  int lane = tid & 63, w = tid >> 6;

  // single-pass gate: 4 threads per row, 48 elems each -> As + s2
  {
    int row = tid >> 2, part = tid & 3;
    size_t g = (size_t)(m0 + row);
    float s2 = 0.f;
    #pragma unroll
    for (int i = 0; i < 48; i += 8){
      int k = part*48 + i;
      float y[8], y1[8], y2[8], y3[8], xh[8], z[8];
      const float* yp = Y + g*DI + k;
      const float* p1 = YP3 + g*DI + k;
      const float* p2 = YP3 + PS + g*DI + k;
      const float* p3 = YP3 + 2*PS + g*DI + k;
      const float* xp = XBC + g*CD + k;
      const float* zp = ZX + g*ZD + k;
      *(float4*)&y[0] = *(const float4*)yp;   *(float4*)&y[4] = *(const float4*)(yp+4);
      *(float4*)&y1[0] = *(const float4*)p1;  *(float4*)&y1[4] = *(const float4*)(p1+4);
      *(float4*)&y2[0] = *(const float4*)p2;  *(float4*)&y2[4] = *(const float4*)(p2+4);
      *(float4*)&y3[0] = *(const float4*)p3;  *(float4*)&y3[4] = *(const float4*)(p3+4);
      *(float4*)&xh[0] = *(const float4*)xp;  *(float4*)&xh[4] = *(const float4*)(xp+4);
      *(float4*)&z[0] = *(const float4*)zp;   *(float4*)&z[4] = *(const float4*)(zp+4);
      float dv = Dv[k/24];
      short8 o;
      #pragma unroll
      for (int j = 0; j < 8; j++){
        float gv = (y[j]+y1[j]+y2[j]+y3[j] + dv*xh[j]) * silu_f(z[j]);
        s2 += gv*gv;
        o[j] = bf16s(gv * nw[k+j]);
      }
      *(short8*)&As[row*LDA + k] = o;
    }
    s2 += __shfl_xor(s2, 1); s2 += __shfl_xor(s2, 2);
    if (part == 0) sRs[row] = rsqrtf(s2 * (1.f/192.f) + 1e-5f);
  }
  __syncthreads();

  int kb = (lane >> 4) * 8;
  for (int nt = 0; nt < 2; ++nt){
    int n0 = nt * 64;
    for (int u = tid; u < 64*CPR; u += 256){
      int row = u / CPR, cc = u % CPR;
      int n = n0 + row;
      short8 wv = {0,0,0,0,0,0,0,0};
      if (n < N) wv = *(const short8*)(W + (size_t)n*K + cc*8);
      *(short8*)&Ws[row*LDA + cc*8] = wv;
    }
    __syncthreads();

    f32x4 acc[4];
    #pragma unroll
    for (int i = 0; i < 4; i++) acc[i] = (f32x4){0.f,0.f,0.f,0.f};
    for (int ks = 0; ks < 6; ++ks){
      short8 b = *(short8*)&Ws[(w*16 + (lane&15))*LDA + ks*32 + kb];
      #pragma unroll
      for (int i = 0; i < 4; i++){
        short8 a = *(short8*)&As[(i*16 + (lane&15))*LDA + ks*32 + kb];
        acc[i] = __builtin_amdgcn_mfma_f32_16x16x32_bf16(a, b, acc[i], 0, 0, 0);
      }
    }

    int nn = n0 + w*16 + (lane & 15);
    if (nn < N){
      #pragma unroll
      for (int i = 0; i < 4; i++){
        int lrow0 = i*16 + ((lane >> 4) << 2);
        #pragma unroll
        for (int r = 0; r < 4; r++)
          Ct[lrow0 + r][nn] = acc[i][r] * sRs[lrow0 + r];
      }
    }
    __syncthreads();
  }

  // epilogue: residual add + LN over the full 96-wide row
  int row = tid >> 2, part = tid & 3;
  size_t g = (size_t)(m0 + row)*96 + part*24;
  float sv[24];
  float s = 0.f, s2 = 0.f;
  #pragma unroll
  for (int i = 0; i < 24; i += 4){
    float4 rv = *(const float4*)(Rold + g + i);
    float v0 = Ct[row][part*24 + i + 0] + rv.x;
    float v1 = Ct[row][part*24 + i + 1] + rv.y;
    float v2 = Ct[row][part*24 + i + 2] + rv.z;
    float v3 = Ct[row][part*24 + i + 3] + rv.w;
    sv[i] = v0; sv[i+1] = v1; sv[i+2] = v2; sv[i+3] = v3;
    s += v0+v1+v2+v3;
    s2 += v0*v0+v1*v1+v2*v2+v3*v3;
  }
  s += __shfl_xor(s, 1); s += __shfl_xor(s, 2);
  s2 += __shfl_xor(s2, 1); s2 += __shfl_xor(s2, 2);
  float mu = s * (1.f/96.f);
  float rstd = rsqrtf(s2 * (1.f/96.f) - mu*mu + 1e-5f);
  #pragma unroll
  for (int i = 0; i < 24; i += 4)
    *(float4*)(Rnew + g + i) = make_float4(sv[i], sv[i+1], sv[i+2], sv[i+3]);
  ushort* Ub = (ushort*)Ubo;
  #pragma unroll
  for (int v8 = 0; v8 < 3; ++v8){
    short8 o;
    #pragma unroll
    for (int j = 0; j < 8; j++){
      int c = part*24 + v8*8 + j;
      o[j] = bf16s((sv[v8*8+j]-mu)*rstd*lnw[c] + lnb[c]);
    }
    *(short8*)(Ub + g + v8*8) = o;
  }
}

// ---------------------------------------------------------------------------
// 5) fused: causal conv+bias+silu  |  dt/dA
#define NCONV (NSEQ*LSEQ*(CD/4))          // 983040
__global__ void k_convdt(const float* __restrict__ ZX, const float* __restrict__ cw,
                         const float* __restrict__ cb, const float* __restrict__ dtb,
                         const float* __restrict__ alog,
                         float* __restrict__ XBC, float* __restrict__ DT,
                         float* __restrict__ DA){
  int idx = blockIdx.x*blockDim.x + threadIdx.x;
  if (idx < NCONV){
    int c4 = idx % (CD/4); int t = (idx/(CD/4)) % LSEQ; int s = idx/((CD/4)*LSEQ);
    int c = c4*4;
    float4 acc = *(const float4*)(cb + c);
    #pragma unroll
    for (int k = 0; k < 4; k++){
      int tt = t - 3 + k;
      if (tt >= 0){
        float4 v = *(const float4*)(ZX + ((size_t)(s*LSEQ + tt))*ZD + DI + c);
        acc.x = fmaf(v.x, cw[(c+0)*4+k], acc.x);
        acc.y = fmaf(v.y, cw[(c+1)*4+k], acc.y);
        acc.z = fmaf(v.z, cw[(c+2)*4+k], acc.z);
        acc.w = fmaf(v.w, cw[(c+3)*4+k], acc.w);
      }
    }
    float4 r;
    r.x = silu_f(acc.x); r.y = silu_f(acc.y);
    r.z = silu_f(acc.z); r.w = silu_f(acc.w);
    *(float4*)(XBC + ((size_t)(s*LSEQ + t))*CD + c) = r;
  } else if (idx < NCONV + NROW){
    int row = idx - NCONV;
    #pragma unroll
    for (int h = 0; h < 8; h++){
      float xr = ZX[(size_t)row*ZD + 512 + h] + dtb[h];
      float dt = (xr > 20.f) ? xr : log1pf(expf(xr));
      DT[row*8 + h] = dt;
      DA[row*8 + h] = expf(-expf(alog[h]) * dt);
    }
  }
}

// ---------------------------------------------------------------------------
// 7a) chunked scan pass A: local scan, PLAIN stores into per-nblk partials.
__global__ __launch_bounds__(192)
void k_scanA(const float* __restrict__ XBC, const float* __restrict__ DT,
             const float* __restrict__ DA, float* __restrict__ Y,
             float* __restrict__ YP3, float* __restrict__ Sbuf,
             float* __restrict__ Pbuf){
  int bid = blockIdx.x;
  int c = bid & (NCH-1);
  int nblk = (bid >> 3) & 3;
  int s = bid >> 5;
  int tid = threadIdx.x;       // p
  int h = tid / HD;
  int n0 = nblk*16;
  int t0 = c*LC;

  __shared__ float sDT[LC*8];
  __shared__ float sDA[LC*8];
  __shared__ float sB[LC][16];
  __shared__ float sC[LC][16];
  {
    const float4* s1 = (const float4*)(DT + ((size_t)s*LSEQ + t0)*8);
    const float4* s2 = (const float4*)(DA + ((size_t)s*LSEQ + t0)*8);
    float4* d1 = (float4*)sDT; float4* d2 = (float4*)sDA;
    for (int i = tid; i < LC*2; i += 192){ d1[i] = s1[i]; d2[i] = s2[i]; }
  }
  const float* xb = XBC + (size_t)s*LSEQ*CD;
  for (int i = tid; i < LC*4; i += 192){
    int row = i >> 2, q = (i & 3) * 4;
    const float* src = xb + (size_t)(t0 + row)*CD + 192;
    *(float4*)&sB[row][q] = *(const float4*)(src + n0 + q);
    *(float4*)&sC[row][q] = *(const float4*)(src + 64 + n0 + q);
  }
  __syncthreads();

  float* dst = (nblk == 0) ? Y : (YP3 + (size_t)(nblk-1)*NROW*DI);
  float* yout = dst + ((size_t)s*LSEQ + t0)*DI + tid;

  float hr[16];
  #pragma unroll
  for (int n = 0; n < 16; n++) hr[n] = 0.f;

  float xq[4], xn[4];
  #pragma unroll
  for (int i = 0; i < 4; i++) xq[i] = xb[(size_t)(t0+i)*CD + tid];

  for (int tc = 0; tc < LC; tc += 4){
    if (tc + 4 < LC){
      #pragma unroll
      for (int i = 0; i < 4; i++) xn[i] = xb[(size_t)(t0+tc+4+i)*CD + tid];
    }
    #pragma unroll
    for (int t4 = 0; t4 < 4; ++t4){
      int t = tc + t4;
      float dAv = sDA[t*8 + h];
      float dtv = sDT[t*8 + h];
      float b[16], cv[16];
      *(float4*)&b[0]  = *(const float4*)&sB[t][0];
      *(float4*)&b[4]  = *(const float4*)&sB[t][4];
      *(float4*)&b[8]  = *(const float4*)&sB[t][8];
      *(float4*)&b[12] = *(const float4*)&sB[t][12];
      *(float4*)&cv[0]  = *(const float4*)&sC[t][0];
      *(float4*)&cv[4]  = *(const float4*)&sC[t][4];
      *(float4*)&cv[8]  = *(const float4*)&sC[t][8];
      *(float4*)&cv[12] = *(const float4*)&sC[t][12];
      float dtx = dtv * xq[t4];
      float a0 = 0.f, a1 = 0.f, a2 = 0.f, a3 = 0.f;
      #pragma unroll
      for (int n = 0; n < 4; n++){
        hr[n]    = fmaf(dAv, hr[n],    dtx * b[n]);    a0 = fmaf(hr[n],    cv[n],    a0);
        hr[4+n]  = fmaf(dAv, hr[4+n],  dtx * b[4+n]);  a1 = fmaf(hr[4+n],  cv[4+n],  a1);
        hr[8+n]  = fmaf(dAv, hr[8+n],  dtx * b[8+n]);  a2 = fmaf(hr[8+n],  cv[8+n],  a2);
        hr[12+n] = fmaf(dAv, hr[12+n], dtx * b[12+n]); a3 = fmaf(hr[12+n], cv[12+n], a3);
      }
      yout[(size_t)t*DI] = (a0 + a1) + (a2 + a3);
    }
    #pragma unroll
    for (int i = 0; i < 4; i++) xq[i] = xn[i];
  }

  float* Sp = Sbuf + ((size_t)bid*192 + tid)*16;
  #pragma unroll
  for (int n = 0; n < 16; n += 4)
    *(float4*)(Sp + n) = make_float4(hr[n], hr[n+1], hr[n+2], hr[n+3]);
  if (tid < 8){
    float p = 1.f;
    for (int t = 0; t < LC; t++) p *= sDA[t*8 + tid];
    Pbuf[((size_t)s*NCH + c)*8 + tid] = p;
  }
}

// ---------------------------------------------------------------------------
// 7b) chunked scan pass C: partial += cp_t * (C_t . H_in)  (race-free RMW).
__global__ __launch_bounds__(192)
void k_scanC(const float* __restrict__ XBC, const float* __restrict__ DA,
             const float* __restrict__ Sbuf, const float* __restrict__ Pbuf,
             float* __restrict__ Y, float* __restrict__ YP3){
  int bid = blockIdx.x;
  int c = bid & (NCH-1);
  if (c == 0) return;
  int nblk = (bid >> 3) & 3;
  int s = bid >> 5;
  int tid = threadIdx.x;
  int h = tid / HD;
  int n0 = nblk*16;
  int t0 = c*LC;

  __shared__ float sC[LC][16];
  __shared__ float scp[LC*8];
  __shared__ float sP[NCH*8];

  const float* xb = XBC + (size_t)s*LSEQ*CD;
  for (int i = tid; i < LC*4; i += 192){
    int row = i >> 2, q = (i & 3) * 4;
    *(float4*)&sC[row][q] =
      *(const float4*)(xb + (size_t)(t0 + row)*CD + 192 + 64 + n0 + q);
  }
  {
    const float* asrc = DA + ((size_t)s*LSEQ + t0)*8;
    for (int i = tid; i < LC*8; i += 192) scp[i] = asrc[i];
  }
  if (tid < NCH*8) sP[tid] = Pbuf[(size_t)s*NCH*8 + tid];
  __syncthreads();

  if (tid < 8){
    float p = 1.f;
    for (int t = 0; t < LC; t++){ p *= scp[t*8 + tid]; scp[t*8 + tid] = p; }
  }
  float H[16];
  #pragma unroll
  for (int n = 0; n < 16; n++) H[n] = 0.f;
  for (int cc = 0; cc < c; ++cc){
    const float* Sp = Sbuf + ((((size_t)(s*4 + nblk)*NCH) + cc)*192 + tid)*16;
    float Pv = sP[cc*8 + h];
    float sv[16];
    #pragma unroll
    for (int n = 0; n < 16; n += 4) *(float4*)&sv[n] = *(const float4*)(Sp + n);
    #pragma unroll
    for (int n = 0; n < 16; n++) H[n] = fmaf(Pv, H[n], sv[n]);
  }
  __syncthreads();

  float* dst = (nblk == 0) ? Y : (YP3 + (size_t)(nblk-1)*NROW*DI);
  float* yout = dst + ((size_t)s*LSEQ + t0)*DI + tid;

  for (int t = 0; t < LC; t += 4){
    float yold[4];
    #pragma unroll
    for (int i = 0; i < 4; i++) yold[i] = yout[(size_t)(t+i)*DI];
    #pragma unroll
    for (int i = 0; i < 4; i++){
      float dot = 0.f;
      #pragma unroll
      for (int n = 0; n < 16; n++) dot = fmaf(sC[t+i][n], H[n], dot);
      yout[(size_t)(t+i)*DI] = yold[i] + scp[(t+i)*8 + h]*dot;
    }
  }
}

// ---------------------------------------------------------------------------
// 9) merge 12 directions -> output
__global__ void k_merge(const float* __restrict__ F, float* __restrict__ out){
  int idx = blockIdx.x*blockDim.x + threadIdx.x;
  if (idx >= 2*96*512) return;
  int r = idx % 512; int m = (idx/512) % 96; int b = idx/(512*96);
  int i = r >> 6, j = (r >> 3) & 7, k = r & 7;
  int ti = r;
  int tj = j*64 + k*8 + i;
  int tk = k*64 + i*8 + j;
  const float* Fb = F + (size_t)(b*12)*LSEQ*DM;
  float acc = 0.f;
  acc += Fb[(0*LSEQ + ti)*DM + m]        + Fb[(1*LSEQ + ti)*DM + m];
  acc += Fb[(2*LSEQ + (511-ti))*DM + m]  + Fb[(3*LSEQ + (511-ti))*DM + m];
  acc += Fb[(4*LSEQ + tj)*DM + m]        + Fb[(5*LSEQ + tj)*DM + m];
  acc += Fb[(6*LSEQ + (511-tj))*DM + m]  + Fb[(7*LSEQ + (511-tj))*DM + m];
  acc += Fb[(8*LSEQ + tk)*DM + m]        + Fb[(9*LSEQ + tk)*DM + m];
  acc += Fb[(10*LSEQ + (511-tk))*DM + m] + Fb[(11*LSEQ + (511-tk))*DM + m];
  out[idx] = acc * (1.f/12.f);
}

// ---------------------------------------------------------------------------
extern "C" void kernel_launch(void* const* d_in, const int* in_sizes, int n_in,
                              void* d_out, int out_size, void* d_ws, size_t ws_size,
                              hipStream_t stream){
  const float* x        = (const float*)d_in[0];
  const float* ds_ln_w  = (const float*)d_in[1];
  const float* ds_ln_b  = (const float*)d_in[2];
  const float* ds_red_w = (const float*)d_in[3];
  const float* norm1_w  = (const float*)d_in[4];
  const float* norm1_b  = (const float*)d_in[5];
  const float* in_proj_w= (const float*)d_in[6];
  const float* conv_w   = (const float*)d_in[7];
  const float* conv_b   = (const float*)d_in[8];
  const float* dt_bias  = (const float*)d_in[9];
  const float* A_log    = (const float*)d_in[10];
  const float* Dv       = (const float*)d_in[11];
  const float* ssm_nw   = (const float*)d_in[12];
  const float* out_pw   = (const float*)d_in[13];
  const float* norm2_w  = (const float*)d_in[14];
  const float* norm2_b  = (const float*)d_in[15];
  const float* fc1_w    = (const float*)d_in[16];
  const float* fc1_b    = (const float*)d_in[17];
  const float* fc2_w    = (const float*)d_in[18];
  const float* fc2_b    = (const float*)d_in[19];
  const float* normf_w  = (const float*)d_in[20];
  const float* normf_b  = (const float*)d_in[21];
  float* out = (float*)d_out;

  float* ws = (float*)d_ws;
  const size_t NRES = 2*96*512;
  const size_t NHS  = (size_t)NROW*DM;
  const size_t NZX  = (size_t)NROW*ZD;
  const size_t NXBC = (size_t)NROW*CD;
  const size_t NDT  = (size_t)NROW*NH;
  const size_t NY   = (size_t)NROW*DI;
  const size_t NSB  = (size_t)NSEQ*4*NCH*192*16;
  float* res = ws;
  float* H   = res + NRES;        // residual for layer 0 (= hs)
  float* RA  = H + NHS;
  float* U   = RA + NHS;          // f32 U for final LN / bf16 Ub alias
  float* ZX  = U + NHS;
  float* XBC = ZX + NZX;
  float* DT  = XBC + NXBC;
  float* DA  = DT + NDT;
  float* Y   = DA + NDT;
  float* YP3 = Y + NY;
  float* Sbuf= YP3 + 3*NY;
  float* Pbuf= Sbuf + NSB;
  float* RB  = Pbuf + (size_t)NSEQ*NCH*8;
  float* Wb_f= RB + NHS;
  __hip_bfloat16* Ub  = (__hip_bfloat16*)U;
  __hip_bfloat16* Wb  = (__hip_bfloat16*)Wb_f;
  __hip_bfloat16* T1b = (__hip_bfloat16*)XBC;   // XBC dead once fc1 runs

  // downsample + weight convert (merged)
  k_dswcvt<<<1024 + WCB, 128, 0, stream>>>(
      x, ds_ln_w, ds_ln_b, ds_red_w, res,
      in_proj_w, out_pw, fc1_w, fc2_w, Wb);
  // build hs row + layer-0 LN1 -> H, Ub
  k_build_ln<<<NROW, 128, 0, stream>>>(res, H, Ub, norm1_w, norm1_b);

  const int MB = NROW/64;     // 192
  const int SCB = NSEQ*4*NCH; // 768
  const int CDB = (NCONV + NROW + 255)/256;

  for (int l = 0; l < 2; l++){
    const float* cw  = conv_w + (size_t)l*CD*4, * cb = conv_b + (size_t)l*CD;
    const float* dtb = dt_bias + l*NH, * alog = A_log + l*NH, * dvl = Dv + l*NH;
    const float* snw = ssm_nw + (size_t)l*DI;
    const float* n2w = norm2_w + l*DM,  * n2b = norm2_b + l*DM;
    const float* f1b = fc1_b + (size_t)l*DI;
    const float* f2b = fc2_b + (size_t)l*DM;
    const ushort* Wip = (const ushort*)(Wb + (size_t)l*WPL);
    const ushort* Wop = Wip + WIP;
    const ushort* Wf1 = Wop + WOP;
    const ushort* Wf2 = Wf1 + WF1;

    const float* Rold = (l == 0) ? H : RB;   // residual entering this layer
    float* Rmid = RA;                        // residual after attn part
    float* Rnext = RB;                       // residual after MLP

    // in_proj: Ub @ Wip^T -> ZX (f32)
    k_gemm_m2<0,0><<<dim3(MB, 9), 256, 0, stream>>>(
        (const ushort*)Ub, Wip, nullptr, ZX, nullptr, ZD, DM, 1);
    // conv + silu | dt/dA
    k_convdt<<<CDB, 256, 0, stream>>>(ZX, cw, cb, dtb, alog, XBC, DT, DA);
    k_scanA<<<SCB, 192, 0, stream>>>(XBC, DT, DA, Y, YP3, Sbuf, Pbuf);
    k_scanC<<<SCB, 192, 0, stream>>>(XBC, DA, Sbuf, Pbuf, Y, YP3);
    // out_proj fused: gate prologue + Rmid = Rold + S ; Ub = LN2(Rmid)
    k_gemm_gate<<<MB, 256, 0, stream>>>(
        Y, YP3, XBC, ZX, dvl, snw, Wop, Rold, Rmid, n2w, n2b, Ub);
    // fc1 + gelu -> T1b (bf16)
    k_gemm_m2<1,1><<<dim3(MB, 3), 256, 0, stream>>>(
        (const ushort*)Ub, Wf1, f1b, nullptr, T1b, DI, DM, 1);
    // fc2 fused: Rnext = Rmid + T1b@Wf2^T + f2b ; U = LN(Rnext)
    if (l == 0){
      k_gemm_fuse<0><<<MB, 256, 0, stream>>>(
          (const ushort*)T1b, Wf2, f2b, Rmid, Rnext,
          norm1_w + DM, norm1_b + DM, Ub);
    } else {
      k_gemm_fuse<1><<<MB, 256, 0, stream>>>(
          (const ushort*)T1b, Wf2, f2b, Rmid, Rnext,
          normf_w, normf_b, U);
    }
  }

  k_merge<<<(2*96*512 + 255)/256, 256, 0, stream>>>(U, out);
}

// Round 16
// 403.161 us; speedup vs baseline: 1.0463x; 1.0463x over previous
//
#include <hip/hip_runtime.h>
#include <hip/hip_bf16.h>
#include <math.h>

// Problem constants
#define DM 96
#define DI 192
#define DSTATE 64
#define NH 8
#define HD 24
#define CD 320
#define ZD 520
#define LSEQ 512
#define NSEQ 24            // B(2) * 12 directions
#define NROW (NSEQ*LSEQ)   // 12288
#define LC 64              // scan chunk length
#define NCH (LSEQ/LC)      // 8 chunks

typedef __attribute__((ext_vector_type(8))) short short8;
typedef __attribute__((ext_vector_type(4))) float f32x4;

__device__ __forceinline__ float wave_sum64(float v){
  #pragma unroll
  for (int o = 32; o > 0; o >>= 1) v += __shfl_down(v, o);
  return v;
}

__device__ __forceinline__ float silu_f(float x){
  return x / (1.f + expf(-x));
}

__device__ __forceinline__ short bf16s(float v){
  __hip_bfloat16 b = __float2bfloat16(v);
  return *reinterpret_cast<short*>(&b);
}

// ---------------------------------------------------------------------------
// 1+0) merged: downsample (blocks 0..1023) | weight bf16 convert (rest)
#define WIP 49920            // 520*96
#define WOP 18432            // 96*192
#define WF1 18432            // 192*96
#define WF2 18432            // 96*192
#define WPL (WIP+WOP+WF1+WF2)  // 105216
#define WCB ((2*WPL + 127)/128)  // wcvt blocks
__global__ void k_dswcvt(const float* __restrict__ x,
                         const float* __restrict__ lnw,
                         const float* __restrict__ lnb,
                         const float* __restrict__ redw,
                         float* __restrict__ res,
                         const float* __restrict__ ipw, const float* __restrict__ opw,
                         const float* __restrict__ f1w, const float* __restrict__ f2w,
                         __hip_bfloat16* __restrict__ Wb){
  int tid = threadIdx.x;
  if (blockIdx.x >= 1024){
    int idx = (blockIdx.x - 1024)*128 + tid;
    if (idx < 2*WPL){
      int l = idx / WPL, r = idx % WPL;
      float v;
      if (r < WIP)                 v = ipw[(size_t)l*WIP + r];
      else if (r < WIP+WOP)        v = opw[(size_t)l*WOP + (r-WIP)];
      else if (r < WIP+WOP+WF1)    v = f1w[(size_t)l*WF1 + (r-WIP-WOP)];
      else                         v = f2w[(size_t)l*WF2 + (r-WIP-WOP-WF1)];
      Wb[idx] = __float2bfloat16(v);
    }
    return;
  }
  int vox = blockIdx.x;
  int b = vox >> 9; int r = vox & 511;
  int i = r >> 6, j = (r >> 3) & 7, k = r & 7;
  __shared__ float t[384];
  __shared__ float sm[4];
  for (int f = tid; f < 384; f += 128){
    int c = f >> 3; int di = (f >> 2) & 1, dj = (f >> 1) & 1, dk = f & 1;
    int X = 2*i + di, Y = 2*j + dj, Z = 2*k + dk;
    t[f] = x[(((b*48 + c)*16 + X)*16 + Y)*16 + Z];
  }
  __syncthreads();
  float s = 0.f, s2 = 0.f;
  for (int f = tid; f < 384; f += 128){ float v = t[f]; s += v; s2 += v*v; }
  s = wave_sum64(s); s2 = wave_sum64(s2);
  int lane = tid & 63, wv = tid >> 6;
  if (lane == 0){ sm[wv] = s; sm[2+wv] = s2; }
  __syncthreads();
  float mean = (sm[0] + sm[1]) * (1.f/384.f);
  float var  = (sm[2] + sm[3]) * (1.f/384.f) - mean*mean;
  float rstd = rsqrtf(var + 1e-5f);
  __syncthreads();
  for (int f = tid; f < 384; f += 128) t[f] = (t[f]-mean)*rstd*lnw[f] + lnb[f];
  __syncthreads();
  if (tid < 96){
    const float* wrow = redw + tid*384;
    float acc = 0.f;
    #pragma unroll 4
    for (int f = 0; f < 384; f++) acc = fmaf(t[f], wrow[f], acc);
    res[((b*96 + tid)*512) + r] = acc;
  }
}

// ---------------------------------------------------------------------------
// 2+3) build H row + layer-0 LN1 -> Ub (bf16).  grid = NROW, 128 thr.
__global__ void k_build_ln(const float* __restrict__ res, float* __restrict__ H,
                           __hip_bfloat16* __restrict__ Ub,
                           const float* __restrict__ w, const float* __restrict__ bias){
  int row = blockIdx.x;           // s*LSEQ + t
  int s = row >> 9; int t = row & 511;
  int tid = threadIdx.x;
  float v = 0.f;
  if (tid < DM){
    int b = s / 12, d = s % 12;
    int tt = (d & 2) ? (511 - t) : t;
    int a = tt >> 6, bb = (tt >> 3) & 7, cc = tt & 7;
    int i, j, k;
    int g = d >> 2; bool sw = d & 1;
    if (g == 0){ if (!sw){ i=a; j=bb; k=cc; } else { i=a; k=bb; j=cc; } }
    else if (g == 1){ if (!sw){ j=a; k=bb; i=cc; } else { j=a; i=bb; k=cc; } }
    else { if (!sw){ k=a; i=bb; j=cc; } else { k=a; j=bb; i=cc; } }
    v = res[((b*96 + tid)*512) + (i*64 + j*8 + k)];
  }
  float sv = wave_sum64(v), s2 = wave_sum64(v*v);
  __shared__ float sm[4];
  int lane = tid & 63, wv = tid >> 6;
  if (lane == 0){ sm[wv] = sv; sm[2+wv] = s2; }
  __syncthreads();
  float mean = (sm[0] + sm[1]) * (1.f/96.f);
  float var  = (sm[2] + sm[3]) * (1.f/96.f) - mean*mean;
  float rstd = rsqrtf(var + 1e-5f);
  if (tid < DM){
    H[(size_t)row*DM + tid] = v;
    Ub[(size_t)row*DM + tid] = __float2bfloat16((v-mean)*rstd*w[tid] + bias[tid]);
  }
}

// ---------------------------------------------------------------------------
// 4a) plain MFMA GEMM (bf16 A), full-K LDS stage, TPG n-tiles per y-block.
#define LDA 200   // LDS row stride in ushorts
template<int ACT, int OBF>
__global__ __launch_bounds__(256)
void k_gemm_m2(const ushort* __restrict__ A, const ushort* __restrict__ W,
               const float* __restrict__ bias, float* __restrict__ C,
               __hip_bfloat16* __restrict__ Cb, int N, int K, int TPG){
  __shared__ ushort As[64*LDA];
  __shared__ ushort Ws[64*LDA];
  int m0 = blockIdx.x * 64;
  int tid = threadIdx.x;
  int lane = tid & 63, w = tid >> 6;
  int CPR = K >> 3;
  for (int u = tid; u < 64*CPR; u += 256){
    int row = u / CPR, cc = u % CPR;
    *(short8*)&As[row*LDA + cc*8] =
        *(const short8*)(A + (size_t)(m0+row)*K + cc*8);
  }
  __syncthreads();

  int ntiles = (N + 63) >> 6;
  int nt0 = blockIdx.y * TPG;
  int nt1 = nt0 + TPG; if (nt1 > ntiles) nt1 = ntiles;
  int kb = (lane >> 4) * 8;

  for (int nt = nt0; nt < nt1; ++nt){
    int n0 = nt * 64;
    for (int u = tid; u < 64*CPR; u += 256){
      int row = u / CPR, cc = u % CPR;
      int n = n0 + row;
      short8 wv = {0,0,0,0,0,0,0,0};
      if (n < N) wv = *(const short8*)(W + (size_t)n*K + cc*8);
      *(short8*)&Ws[row*LDA + cc*8] = wv;
    }
    __syncthreads();

    f32x4 acc[4];
    #pragma unroll
    for (int i = 0; i < 4; i++) acc[i] = (f32x4){0.f,0.f,0.f,0.f};
    for (int ks = 0; ks < (K >> 5); ++ks){
      short8 b = *(short8*)&Ws[(w*16 + (lane&15))*LDA + ks*32 + kb];
      #pragma unroll
      for (int i = 0; i < 4; i++){
        short8 a = *(short8*)&As[(i*16 + (lane&15))*LDA + ks*32 + kb];
        acc[i] = __builtin_amdgcn_mfma_f32_16x16x32_bf16(a, b, acc[i], 0, 0, 0);
      }
    }

    int nn = n0 + w*16 + (lane & 15);
    if (nn < N){
      float bv = bias ? bias[nn] : 0.f;
      #pragma unroll
      for (int i = 0; i < 4; i++){
        int lrow0 = i*16 + ((lane >> 4) << 2);
        #pragma unroll
        for (int r = 0; r < 4; r++){
          float v = acc[i][r] + bv;
          if (ACT == 1) v = 0.5f*v*(1.f + erff(v*0.70710678118654752f));
          size_t off = (size_t)(m0 + lrow0 + r)*N + nn;
          if (OBF) Cb[off] = __float2bfloat16(v);
          else     C[off] = v;
        }
      }
    }
    __syncthreads();
  }
}

// ---------------------------------------------------------------------------
// 4b) fused-output GEMM: N==96, K==192, grid (192,1).
//     S = A.W^T (+bias) + Rold ;  Rnew = S ;  U = LN(S)*lnw + lnb.
template<int UF32>
__global__ __launch_bounds__(256)
void k_gemm_fuse(const ushort* __restrict__ A, const ushort* __restrict__ W,
                 const float* __restrict__ bias,
                 const float* __restrict__ Rold, float* __restrict__ Rnew,
                 const float* __restrict__ lnw, const float* __restrict__ lnb,
                 void* __restrict__ Uo){
  __shared__ ushort As[64*LDA];
  __shared__ ushort Ws[64*LDA];
  __shared__ float Ct[64][100];
  const int K = 192, N = 96, CPR = 24;
  int m0 = blockIdx.x * 64;
  int tid = threadIdx.x;
  int lane = tid & 63, w = tid >> 6;
  for (int u = tid; u < 64*CPR; u += 256){
    int row = u / CPR, cc = u % CPR;
    *(short8*)&As[row*LDA + cc*8] =
        *(const short8*)(A + (size_t)(m0+row)*K + cc*8);
  }
  __syncthreads();

  int kb = (lane >> 4) * 8;
  for (int nt = 0; nt < 2; ++nt){
    int n0 = nt * 64;
    for (int u = tid; u < 64*CPR; u += 256){
      int row = u / CPR, cc = u % CPR;
      int n = n0 + row;
      short8 wv = {0,0,0,0,0,0,0,0};
      if (n < N) wv = *(const short8*)(W + (size_t)n*K + cc*8);
      *(short8*)&Ws[row*LDA + cc*8] = wv;
    }
    __syncthreads();

    f32x4 acc[4];
    #pragma unroll
    for (int i = 0; i < 4; i++) acc[i] = (f32x4){0.f,0.f,0.f,0.f};
    for (int ks = 0; ks < 6; ++ks){
      short8 b = *(short8*)&Ws[(w*16 + (lane&15))*LDA + ks*32 + kb];
      #pragma unroll
      for (int i = 0; i < 4; i++){
        short8 a = *(short8*)&As[(i*16 + (lane&15))*LDA + ks*32 + kb];
        acc[i] = __builtin_amdgcn_mfma_f32_16x16x32_bf16(a, b, acc[i], 0, 0, 0);
      }
    }

    int nn = n0 + w*16 + (lane & 15);
    if (nn < N){
      float bv = bias ? bias[nn] : 0.f;
      #pragma unroll
      for (int i = 0; i < 4; i++){
        int lrow0 = i*16 + ((lane >> 4) << 2);
        #pragma unroll
        for (int r = 0; r < 4; r++)
          Ct[lrow0 + r][nn] = acc[i][r] + bv;
      }
    }
    __syncthreads();
  }

  // epilogue: residual add + LN over the full 96-wide row
  int row = tid >> 2, part = tid & 3;
  size_t g = (size_t)(m0 + row)*96 + part*24;
  float sv[24];
  float s = 0.f, s2 = 0.f;
  #pragma unroll
  for (int i = 0; i < 24; i += 4){
    float4 rv = *(const float4*)(Rold + g + i);
    float v0 = Ct[row][part*24 + i + 0] + rv.x;
    float v1 = Ct[row][part*24 + i + 1] + rv.y;
    float v2 = Ct[row][part*24 + i + 2] + rv.z;
    float v3 = Ct[row][part*24 + i + 3] + rv.w;
    sv[i] = v0; sv[i+1] = v1; sv[i+2] = v2; sv[i+3] = v3;
    s += v0+v1+v2+v3;
    s2 += v0*v0+v1*v1+v2*v2+v3*v3;
  }
  s += __shfl_xor(s, 1); s += __shfl_xor(s, 2);
  s2 += __shfl_xor(s2, 1); s2 += __shfl_xor(s2, 2);
  float mu = s * (1.f/96.f);
  float rstd = rsqrtf(s2 * (1.f/96.f) - mu*mu + 1e-5f);
  #pragma unroll
  for (int i = 0; i < 24; i += 4)
    *(float4*)(Rnew + g + i) = make_float4(sv[i], sv[i+1], sv[i+2], sv[i+3]);
  if (UF32){
    float* Uf = (float*)Uo;
    #pragma unroll
    for (int i = 0; i < 24; i += 4){
      int c = part*24 + i;
      *(float4*)(Uf + g + i) = make_float4(
        (sv[i]  -mu)*rstd*lnw[c]   + lnb[c],
        (sv[i+1]-mu)*rstd*lnw[c+1] + lnb[c+1],
        (sv[i+2]-mu)*rstd*lnw[c+2] + lnb[c+2],
        (sv[i+3]-mu)*rstd*lnw[c+3] + lnb[c+3]);
    }
  } else {
    ushort* Ub = (ushort*)Uo;
    #pragma unroll
    for (int v8 = 0; v8 < 3; ++v8){
      short8 o;
      #pragma unroll
      for (int j = 0; j < 8; j++){
        int c = part*24 + v8*8 + j;
        o[j] = bf16s((sv[v8*8+j]-mu)*rstd*lnw[c] + lnb[c]);
      }
      *(short8*)(Ub + g + v8*8) = o;
    }
  }
}

// ---------------------------------------------------------------------------
// 5) fused: causal conv+bias+silu  |  dt/dA
#define NCONV (NSEQ*LSEQ*(CD/4))          // 983040
__global__ void k_convdt(const float* __restrict__ ZX, const float* __restrict__ cw,
                         const float* __restrict__ cb, const float* __restrict__ dtb,
                         const float* __restrict__ alog,
                         float* __restrict__ XBC, float* __restrict__ DT,
                         float* __restrict__ DA){
  int idx = blockIdx.x*blockDim.x + threadIdx.x;
  if (idx < NCONV){
    int c4 = idx % (CD/4); int t = (idx/(CD/4)) % LSEQ; int s = idx/((CD/4)*LSEQ);
    int c = c4*4;
    float4 acc = *(const float4*)(cb + c);
    #pragma unroll
    for (int k = 0; k < 4; k++){
      int tt = t - 3 + k;
      if (tt >= 0){
        float4 v = *(const float4*)(ZX + ((size_t)(s*LSEQ + tt))*ZD + DI + c);
        acc.x = fmaf(v.x, cw[(c+0)*4+k], acc.x);
        acc.y = fmaf(v.y, cw[(c+1)*4+k], acc.y);
        acc.z = fmaf(v.z, cw[(c+2)*4+k], acc.z);
        acc.w = fmaf(v.w, cw[(c+3)*4+k], acc.w);
      }
    }
    float4 r;
    r.x = silu_f(acc.x); r.y = silu_f(acc.y);
    r.z = silu_f(acc.z); r.w = silu_f(acc.w);
    *(float4*)(XBC + ((size_t)(s*LSEQ + t))*CD + c) = r;
  } else if (idx < NCONV + NROW){
    int row = idx - NCONV;
    #pragma unroll
    for (int h = 0; h < 8; h++){
      float xr = ZX[(size_t)row*ZD + 512 + h] + dtb[h];
      float dt = (xr > 20.f) ? xr : log1pf(expf(xr));
      DT[row*8 + h] = dt;
      DA[row*8 + h] = expf(-expf(alog[h]) * dt);
    }
  }
}

// ---------------------------------------------------------------------------
// 7a) chunked scan pass A: local scan, PLAIN stores into per-nblk partials.
__global__ __launch_bounds__(192)
void k_scanA(const float* __restrict__ XBC, const float* __restrict__ DT,
             const float* __restrict__ DA, float* __restrict__ Y,
             float* __restrict__ YP3, float* __restrict__ Sbuf,
             float* __restrict__ Pbuf){
  int bid = blockIdx.x;
  int c = bid & (NCH-1);
  int nblk = (bid >> 3) & 3;
  int s = bid >> 5;
  int tid = threadIdx.x;       // p
  int h = tid / HD;
  int n0 = nblk*16;
  int t0 = c*LC;

  __shared__ float sDT[LC*8];
  __shared__ float sDA[LC*8];
  __shared__ float sB[LC][16];
  __shared__ float sC[LC][16];
  {
    const float4* s1 = (const float4*)(DT + ((size_t)s*LSEQ + t0)*8);
    const float4* s2 = (const float4*)(DA + ((size_t)s*LSEQ + t0)*8);
    float4* d1 = (float4*)sDT; float4* d2 = (float4*)sDA;
    for (int i = tid; i < LC*2; i += 192){ d1[i] = s1[i]; d2[i] = s2[i]; }
  }
  const float* xb = XBC + (size_t)s*LSEQ*CD;
  for (int i = tid; i < LC*4; i += 192){
    int row = i >> 2, q = (i & 3) * 4;
    const float* src = xb + (size_t)(t0 + row)*CD + 192;
    *(float4*)&sB[row][q] = *(const float4*)(src + n0 + q);
    *(float4*)&sC[row][q] = *(const float4*)(src + 64 + n0 + q);
  }
  __syncthreads();

  float* dst = (nblk == 0) ? Y : (YP3 + (size_t)(nblk-1)*NROW*DI);
  float* yout = dst + ((size_t)s*LSEQ + t0)*DI + tid;

  float hr[16];
  #pragma unroll
  for (int n = 0; n < 16; n++) hr[n] = 0.f;

  float xq[4], xn[4];
  #pragma unroll
  for (int i = 0; i < 4; i++) xq[i] = xb[(size_t)(t0+i)*CD + tid];

  for (int tc = 0; tc < LC; tc += 4){
    if (tc + 4 < LC){
      #pragma unroll
      for (int i = 0; i < 4; i++) xn[i] = xb[(size_t)(t0+tc+4+i)*CD + tid];
    }
    #pragma unroll
    for (int t4 = 0; t4 < 4; ++t4){
      int t = tc + t4;
      float dAv = sDA[t*8 + h];
      float dtv = sDT[t*8 + h];
      float b[16], cv[16];
      *(float4*)&b[0]  = *(const float4*)&sB[t][0];
      *(float4*)&b[4]  = *(const float4*)&sB[t][4];
      *(float4*)&b[8]  = *(const float4*)&sB[t][8];
      *(float4*)&b[12] = *(const float4*)&sB[t][12];
      *(float4*)&cv[0]  = *(const float4*)&sC[t][0];
      *(float4*)&cv[4]  = *(const float4*)&sC[t][4];
      *(float4*)&cv[8]  = *(const float4*)&sC[t][8];
      *(float4*)&cv[12] = *(const float4*)&sC[t][12];
      float dtx = dtv * xq[t4];
      float a0 = 0.f, a1 = 0.f, a2 = 0.f, a3 = 0.f;
      #pragma unroll
      for (int n = 0; n < 4; n++){
        hr[n]    = fmaf(dAv, hr[n],    dtx * b[n]);    a0 = fmaf(hr[n],    cv[n],    a0);
        hr[4+n]  = fmaf(dAv, hr[4+n],  dtx * b[4+n]);  a1 = fmaf(hr[4+n],  cv[4+n],  a1);
        hr[8+n]  = fmaf(dAv, hr[8+n],  dtx * b[8+n]);  a2 = fmaf(hr[8+n],  cv[8+n],  a2);
        hr[12+n] = fmaf(dAv, hr[12+n], dtx * b[12+n]); a3 = fmaf(hr[12+n], cv[12+n], a3);
      }
      yout[(size_t)t*DI] = (a0 + a1) + (a2 + a3);
    }
    #pragma unroll
    for (int i = 0; i < 4; i++) xq[i] = xn[i];
  }

  float* Sp = Sbuf + ((size_t)bid*192 + tid)*16;
  #pragma unroll
  for (int n = 0; n < 16; n += 4)
    *(float4*)(Sp + n) = make_float4(hr[n], hr[n+1], hr[n+2], hr[n+3]);
  if (tid < 8){
    float p = 1.f;
    for (int t = 0; t < LC; t++) p *= sDA[t*8 + tid];
    Pbuf[((size_t)s*NCH + c)*8 + tid] = p;
  }
}

// ---------------------------------------------------------------------------
// 7b) chunked scan pass C: partial += cp_t * (C_t . H_in)  (race-free RMW).
__global__ __launch_bounds__(192)
void k_scanC(const float* __restrict__ XBC, const float* __restrict__ DA,
             const float* __restrict__ Sbuf, const float* __restrict__ Pbuf,
             float* __restrict__ Y, float* __restrict__ YP3){
  int bid = blockIdx.x;
  int c = bid & (NCH-1);
  if (c == 0) return;
  int nblk = (bid >> 3) & 3;
  int s = bid >> 5;
  int tid = threadIdx.x;
  int h = tid / HD;
  int n0 = nblk*16;
  int t0 = c*LC;

  __shared__ float sC[LC][16];
  __shared__ float scp[LC*8];
  __shared__ float sP[NCH*8];

  const float* xb = XBC + (size_t)s*LSEQ*CD;
  for (int i = tid; i < LC*4; i += 192){
    int row = i >> 2, q = (i & 3) * 4;
    *(float4*)&sC[row][q] =
      *(const float4*)(xb + (size_t)(t0 + row)*CD + 192 + 64 + n0 + q);
  }
  {
    const float* asrc = DA + ((size_t)s*LSEQ + t0)*8;
    for (int i = tid; i < LC*8; i += 192) scp[i] = asrc[i];
  }
  if (tid < NCH*8) sP[tid] = Pbuf[(size_t)s*NCH*8 + tid];
  __syncthreads();

  if (tid < 8){
    float p = 1.f;
    for (int t = 0; t < LC; t++){ p *= scp[t*8 + tid]; scp[t*8 + tid] = p; }
  }
  float H[16];
  #pragma unroll
  for (int n = 0; n < 16; n++) H[n] = 0.f;
  for (int cc = 0; cc < c; ++cc){
    const float* Sp = Sbuf + ((((size_t)(s*4 + nblk)*NCH) + cc)*192 + tid)*16;
    float Pv = sP[cc*8 + h];
    float sv[16];
    #pragma unroll
    for (int n = 0; n < 16; n += 4) *(float4*)&sv[n] = *(const float4*)(Sp + n);
    #pragma unroll
    for (int n = 0; n < 16; n++) H[n] = fmaf(Pv, H[n], sv[n]);
  }
  __syncthreads();

  float* dst = (nblk == 0) ? Y : (YP3 + (size_t)(nblk-1)*NROW*DI);
  float* yout = dst + ((size_t)s*LSEQ + t0)*DI + tid;

  for (int t = 0; t < LC; t += 4){
    float yold[4];
    #pragma unroll
    for (int i = 0; i < 4; i++) yold[i] = yout[(size_t)(t+i)*DI];
    #pragma unroll
    for (int i = 0; i < 4; i++){
      float dot = 0.f;
      #pragma unroll
      for (int n = 0; n < 16; n++) dot = fmaf(sC[t+i][n], H[n], dot);
      yout[(size_t)(t+i)*DI] = yold[i] + scp[(t+i)*8 + h]*dot;
    }
  }
}

// ---------------------------------------------------------------------------
// 8) combine partials + D*xh + silu(z) gate + RMSNorm(192) -> bf16 Yb
__global__ __launch_bounds__(192)
void k_gate2(const float* __restrict__ Y, const float* __restrict__ YP3,
             const float* __restrict__ XBC, const float* __restrict__ ZX,
             const float* __restrict__ Dv, const float* __restrict__ nw,
             __hip_bfloat16* __restrict__ Yb){
  int row = blockIdx.x; int tid = threadIdx.x;
  size_t o = (size_t)row*DI + tid;
  const size_t PS = (size_t)NROW*DI;
  float y = Y[o] + YP3[o] + YP3[PS + o] + YP3[2*PS + o];
  int h = tid / 24;
  float xh = XBC[(size_t)row*CD + tid];
  y += Dv[h] * xh;
  float z = ZX[(size_t)row*ZD + tid];
  y *= silu_f(z);
  float s2 = wave_sum64(y*y);
  __shared__ float sm[3];
  int lane = tid & 63, wv = tid >> 6;
  if (lane == 0) sm[wv] = s2;
  __syncthreads();
  float rms = rsqrtf((sm[0]+sm[1]+sm[2]) * (1.f/192.f) + 1e-5f);
  Yb[o] = __float2bfloat16(y * rms * nw[tid]);
}

// ---------------------------------------------------------------------------
// 9) merge 12 directions -> output
__global__ void k_merge(const float* __restrict__ F, float* __restrict__ out){
  int idx = blockIdx.x*blockDim.x + threadIdx.x;
  if (idx >= 2*96*512) return;
  int r = idx % 512; int m = (idx/512) % 96; int b = idx/(512*96);
  int i = r >> 6, j = (r >> 3) & 7, k = r & 7;
  int ti = r;
  int tj = j*64 + k*8 + i;
  int tk = k*64 + i*8 + j;
  const float* Fb = F + (size_t)(b*12)*LSEQ*DM;
  float acc = 0.f;
  acc += Fb[(0*LSEQ + ti)*DM + m]        + Fb[(1*LSEQ + ti)*DM + m];
  acc += Fb[(2*LSEQ + (511-ti))*DM + m]  + Fb[(3*LSEQ + (511-ti))*DM + m];
  acc += Fb[(4*LSEQ + tj)*DM + m]        + Fb[(5*LSEQ + tj)*DM + m];
  acc += Fb[(6*LSEQ + (511-tj))*DM + m]  + Fb[(7*LSEQ + (511-tj))*DM + m];
  acc += Fb[(8*LSEQ + tk)*DM + m]        + Fb[(9*LSEQ + tk)*DM + m];
  acc += Fb[(10*LSEQ + (511-tk))*DM + m] + Fb[(11*LSEQ + (511-tk))*DM + m];
  out[idx] = acc * (1.f/12.f);
}

// ---------------------------------------------------------------------------
extern "C" void kernel_launch(void* const* d_in, const int* in_sizes, int n_in,
                              void* d_out, int out_size, void* d_ws, size_t ws_size,
                              hipStream_t stream){
  const float* x        = (const float*)d_in[0];
  const float* ds_ln_w  = (const float*)d_in[1];
  const float* ds_ln_b  = (const float*)d_in[2];
  const float* ds_red_w = (const float*)d_in[3];
  const float* norm1_w  = (const float*)d_in[4];
  const float* norm1_b  = (const float*)d_in[5];
  const float* in_proj_w= (const float*)d_in[6];
  const float* conv_w   = (const float*)d_in[7];
  const float* conv_b   = (const float*)d_in[8];
  const float* dt_bias  = (const float*)d_in[9];
  const float* A_log    = (const float*)d_in[10];
  const float* Dv       = (const float*)d_in[11];
  const float* ssm_nw   = (const float*)d_in[12];
  const float* out_pw   = (const float*)d_in[13];
  const float* norm2_w  = (const float*)d_in[14];
  const float* norm2_b  = (const float*)d_in[15];
  const float* fc1_w    = (const float*)d_in[16];
  const float* fc1_b    = (const float*)d_in[17];
  const float* fc2_w    = (const float*)d_in[18];
  const float* fc2_b    = (const float*)d_in[19];
  const float* normf_w  = (const float*)d_in[20];
  const float* normf_b  = (const float*)d_in[21];
  float* out = (float*)d_out;

  float* ws = (float*)d_ws;
  const size_t NRES = 2*96*512;
  const size_t NHS  = (size_t)NROW*DM;
  const size_t NZX  = (size_t)NROW*ZD;
  const size_t NXBC = (size_t)NROW*CD;
  const size_t NDT  = (size_t)NROW*NH;
  const size_t NY   = (size_t)NROW*DI;
  const size_t NSB  = (size_t)NSEQ*4*NCH*192*16;
  float* res = ws;
  float* H   = res + NRES;        // residual for layer 0 (= hs)
  float* RA  = H + NHS;
  float* U   = RA + NHS;          // f32 U for final LN / bf16 Ub alias
  float* ZX  = U + NHS;
  float* XBC = ZX + NZX;
  float* DT  = XBC + NXBC;
  float* DA  = DT + NDT;
  float* Y   = DA + NDT;
  float* YP3 = Y + NY;
  float* Sbuf= YP3 + 3*NY;
  float* Pbuf= Sbuf + NSB;
  float* RB  = Pbuf + (size_t)NSEQ*NCH*8;
  float* Yb_f= RB + NHS;
  float* Wb_f= Yb_f + NY/2;
  __hip_bfloat16* Ub  = (__hip_bfloat16*)U;
  __hip_bfloat16* Yb  = (__hip_bfloat16*)Yb_f;
  __hip_bfloat16* Wb  = (__hip_bfloat16*)Wb_f;
  __hip_bfloat16* T1b = (__hip_bfloat16*)XBC;   // XBC dead once fc1 runs

  // downsample + weight convert (merged)
  k_dswcvt<<<1024 + WCB, 128, 0, stream>>>(
      x, ds_ln_w, ds_ln_b, ds_red_w, res,
      in_proj_w, out_pw, fc1_w, fc2_w, Wb);
  // build hs row + layer-0 LN1 -> H, Ub
  k_build_ln<<<NROW, 128, 0, stream>>>(res, H, Ub, norm1_w, norm1_b);

  const int MB = NROW/64;     // 192
  const int SCB = NSEQ*4*NCH; // 768
  const int CDB = (NCONV + NROW + 255)/256;

  for (int l = 0; l < 2; l++){
    const float* cw  = conv_w + (size_t)l*CD*4, * cb = conv_b + (size_t)l*CD;
    const float* dtb = dt_bias + l*NH, * alog = A_log + l*NH, * dvl = Dv + l*NH;
    const float* snw = ssm_nw + (size_t)l*DI;
    const float* n2w = norm2_w + l*DM,  * n2b = norm2_b + l*DM;
    const float* f1b = fc1_b + (size_t)l*DI;
    const float* f2b = fc2_b + (size_t)l*DM;
    const ushort* Wip = (const ushort*)(Wb + (size_t)l*WPL);
    const ushort* Wop = Wip + WIP;
    const ushort* Wf1 = Wop + WOP;
    const ushort* Wf2 = Wf1 + WF1;

    const float* Rold = (l == 0) ? H : RB;   // residual entering this layer
    float* Rmid = RA;                        // residual after attn part
    float* Rnext = RB;                       // residual after MLP

    // in_proj: Ub @ Wip^T -> ZX (f32)
    k_gemm_m2<0,0><<<dim3(MB, 9), 256, 0, stream>>>(
        (const ushort*)Ub, Wip, nullptr, ZX, nullptr, ZD, DM, 1);
    // conv + silu | dt/dA
    k_convdt<<<CDB, 256, 0, stream>>>(ZX, cw, cb, dtb, alog, XBC, DT, DA);
    k_scanA<<<SCB, 192, 0, stream>>>(XBC, DT, DA, Y, YP3, Sbuf, Pbuf);
    k_scanC<<<SCB, 192, 0, stream>>>(XBC, DA, Sbuf, Pbuf, Y, YP3);
    // gate + RMSNorm -> Yb (bf16)
    k_gate2<<<NROW, 192, 0, stream>>>(Y, YP3, XBC, ZX, dvl, snw, Yb);
    // out_proj fused: Rmid = Rold + Yb@Wop^T ; Ub = LN2(Rmid)
    k_gemm_fuse<0><<<MB, 256, 0, stream>>>(
        (const ushort*)Yb, Wop, nullptr, Rold, Rmid, n2w, n2b, Ub);
    // fc1 + gelu -> T1b (bf16)
    k_gemm_m2<1,1><<<dim3(MB, 3), 256, 0, stream>>>(
        (const ushort*)Ub, Wf1, f1b, nullptr, T1b, DI, DM, 1);
    // fc2 fused: Rnext = Rmid + T1b@Wf2^T + f2b ; U = LN(Rnext)
    if (l == 0){
      k_gemm_fuse<0><<<MB, 256, 0, stream>>>(
          (const ushort*)T1b, Wf2, f2b, Rmid, Rnext,
          norm1_w + DM, norm1_b + DM, Ub);
    } else {
      k_gemm_fuse<1><<<MB, 256, 0, stream>>>(
          (const ushort*)T1b, Wf2, f2b, Rmid, Rnext,
          normf_w, normf_b, U);
    }
  }

  k_merge<<<(2*96*512 + 255)/256, 256, 0, stream>>>(U, out);
}